// Round 6
// baseline (767.909 us; speedup 1.0000x reference)
//
#include <hip/hip_runtime.h>
#include <math.h>

typedef __bf16 bf16x8 __attribute__((ext_vector_type(8)));
typedef float f32x4 __attribute__((ext_vector_type(4)));

#define MTOT 32768   // B*N
#define DD   1024
#define NSEQ 4096
#define BB   8

__device__ __forceinline__ void async16(const void* gp, void* lp) {
  __builtin_amdgcn_global_load_lds(
      (__attribute__((address_space(1))) void*)(const_cast<void*>(gp)),
      (__attribute__((address_space(3))) void*)(lp), 16, 0, 0);
}

__device__ __forceinline__ unsigned short f2bf(float f) {
  union { float f; unsigned int u; } v; v.f = f;
  unsigned int r = v.u + 0x7fffu + ((v.u >> 16) & 1u);
  return (unsigned short)(r >> 16);
}
__device__ __forceinline__ float bf2f(unsigned short u) {
  union { unsigned int u; float f; } v; v.u = ((unsigned int)u) << 16; return v.f;
}

// DS byte address of an LDS object (compiler-sanctioned addrspacecast).
__device__ __forceinline__ unsigned lds_off(void* p) {
  return (unsigned)(unsigned long long)
      (__attribute__((address_space(3))) void*)p;
}
// Inline-asm ds_read_b128 with compile-time offset immediate.
// Rule-18: every consumer cluster gated by explicit lgkmcnt + sched_barrier(0).
#define DSRI(dst, base, off) \
  asm volatile("ds_read_b128 %0, %1 offset:" #off : "=v"(dst) : "v"(base))

#define MFMA_ __builtin_amdgcn_mfma_f32_16x16x32_bf16

// ---------------- fp32 -> bf16 convert (x) ----------------
__global__ void cvt_bf16(const float* __restrict__ in, unsigned short* __restrict__ out, int n) {
  int i = (blockIdx.x * blockDim.x + threadIdx.x) * 8;
  if (i >= n) return;
  float4 a = *(const float4*)(in + i);
  float4 b = *(const float4*)(in + i + 4);
  ushort4 o0, o1;
  o0.x = f2bf(a.x); o0.y = f2bf(a.y); o0.z = f2bf(a.z); o0.w = f2bf(a.w);
  o1.x = f2bf(b.x); o1.y = f2bf(b.y); o1.z = f2bf(b.z); o1.w = f2bf(b.w);
  *(ushort4*)(out + i) = o0;
  *(ushort4*)(out + i + 4) = o1;
}

// ---------------- weights: 4 matrices in one dispatch ----------------
__global__ void cvt_w(const float* __restrict__ w0, const float* __restrict__ w1,
                      const float* __restrict__ w2, const float* __restrict__ w3,
                      unsigned short* __restrict__ out) {
  int z = blockIdx.y;
  const float* in = (z == 0) ? w0 : (z == 1) ? w1 : (z == 2) ? w2 : w3;
  int i = (blockIdx.x * blockDim.x + threadIdx.x) * 8;
  float4 a = *(const float4*)(in + i);
  float4 b = *(const float4*)(in + i + 4);
  ushort4 o0, o1;
  o0.x = f2bf(a.x); o0.y = f2bf(a.y); o0.z = f2bf(a.z); o0.w = f2bf(a.w);
  o1.x = f2bf(b.x); o1.y = f2bf(b.y); o1.z = f2bf(b.z); o1.w = f2bf(b.w);
  unsigned short* o = out + (size_t)z * DD * DD;
  *(ushort4*)(o + i) = o0;
  *(ushort4*)(o + i + 4) = o1;
}

// Stage one 128x32 bf16 tile (8 KB) with slot swizzle c^=(r>>1)&3 on the SOURCE
// side (rule 21): LDS stays linear; swizzled ds_reads apply the same XOR.
// 512 16B units, 2 insts/thread at 256 threads.
template<int LDG>
__device__ __forceinline__ void stage128(const unsigned short* __restrict__ g,
                                         int row0, int k0,
                                         unsigned short* lds, int tid) {
#pragma unroll
  for (int l = 0; l < 2; ++l) {
    int u = l * 256 + tid;           // 16B unit
    int r = u >> 2;                  // row 0..127 (4 units per 64B row)
    int c = u & 3;
    int sl = c ^ ((r >> 1) & 3);     // bank-decorrelating slot swizzle
    async16(g + (size_t)(row0 + r) * LDG + k0 + sl * 8, (char*)lds + u * 16);
  }
}

// Stage one 128x64 half-tile with XOR swizzle (attn kernel, BK=64 path).
template<int LDG>
__device__ __forceinline__ void stage_half(const unsigned short* __restrict__ g,
                                           int row0, int k0,
                                           unsigned short* lds, int tid) {
#pragma unroll
  for (int l = 0; l < 2; ++l) {
    int u = l * 512 + tid;
    int r = u >> 3;
    int sl = (u & 7) ^ (r & 7);
    async16(g + (size_t)(row0 + r) * LDG + k0 + sl * 8, (char*)lds + u * 16);
  }
}

// ---------------- unified projection GEMM (128^2 tile, BK=32, 4 blocks/CU) ----
// z: 0=Vr (natural), 1=Vi (natural), 2=K (transposed out + sumsq), 3=Q (same)
__global__ __launch_bounds__(256, 4) void proj_all(
    const unsigned short* __restrict__ xb,
    const unsigned short* __restrict__ Wb,
    const float* __restrict__ bvr, const float* __restrict__ bvi,
    const float* __restrict__ bk,  const float* __restrict__ bq,
    unsigned short* __restrict__ oVr, unsigned short* __restrict__ oVi,
    unsigned short* __restrict__ Kt,  unsigned short* __restrict__ Qt,
    float* __restrict__ rnacc) {
  // 2 dbuf x (A 128x32 + B 128x32) = 32 KB; +transpose scratch => 36 KB total
  __shared__ __align__(16) unsigned short smem[18432];

  const int bx = blockIdx.x;
  const int swz = (bx & 7) * 256 + (bx >> 3);  // bijective XCD swizzle (2048=8*256)
  const int m0 = (swz >> 3) * 128;
  const int n0 = (swz & 7) * 128;
  const int z = blockIdx.z;
  const unsigned short* W = Wb + (size_t)z * DD * DD;
  const float* bias = (z == 0) ? bvr : (z == 1) ? bvi : (z == 2) ? bk : bq;

  const int tid = threadIdx.x;
  const int w = tid >> 6, lane = tid & 63;
  const int wr = w >> 1, wc = w & 1;           // 2x2 wave grid; wave owns 64x64
  const int lq = lane >> 4, lr = lane & 15;
  const int key = (lr >> 1) & 3;               // read-side swizzle key
  const int arow0 = wr * 64 + lr;
  const int brow0 = wc * 64 + lr;

  f32x4 acc[4][4];
#pragma unroll
  for (int i = 0; i < 4; i++)
#pragma unroll
    for (int j = 0; j < 4; j++) acc[i][j] = (f32x4)(0.f);

  const int NT = 32;  // K=1024 / BK=32

  const unsigned sbase = lds_off(smem);
  const unsigned swsl = (unsigned)((lq ^ key) << 4);
  unsigned aA[2], aB[2];
#pragma unroll
  for (int i = 0; i < 2; ++i) {
    aA[i] = sbase + i * 16384u + (unsigned)(arow0 * 64) + swsl;
    aB[i] = sbase + i * 16384u + 8192u + (unsigned)(brow0 * 64) + swsl;
  }

  // prologue: tiles 0,1 -> buf0,buf1
  stage128<1024>(xb, m0, 0,  smem,               tid);
  stage128<1024>(W,  n0, 0,  smem + 4096,        tid);
  stage128<1024>(xb, m0, 32, smem + 8192,        tid);
  stage128<1024>(W,  n0, 32, smem + 8192 + 4096, tid);
  asm volatile("s_waitcnt vmcnt(4)" ::: "memory");
  __builtin_amdgcn_s_barrier();

#pragma unroll
  for (int k = 0; k < NT; ++k) {
    const unsigned rA = aA[k & 1], rB = aB[k & 1];
    bf16x8 Af[4], Bf[4];
    DSRI(Af[0], rA, 0);
    DSRI(Bf[0], rB, 0);    DSRI(Bf[1], rB, 1024);
    DSRI(Bf[2], rB, 2048); DSRI(Bf[3], rB, 3072);
    DSRI(Af[1], rA, 1024); DSRI(Af[2], rA, 2048); DSRI(Af[3], rA, 3072);
    asm volatile("s_waitcnt lgkmcnt(3)" ::: "memory");  // Af[0]+Bf[0..3] landed
    __builtin_amdgcn_sched_barrier(0);
    __builtin_amdgcn_s_setprio(1);
#pragma unroll
    for (int nj = 0; nj < 4; ++nj)
      acc[0][nj] = MFMA_(Af[0], Bf[nj], acc[0][nj], 0, 0, 0);
    asm volatile("s_waitcnt lgkmcnt(0)" ::: "memory");
    __builtin_amdgcn_sched_barrier(0);
#pragma unroll
    for (int mi = 1; mi < 4; ++mi)
#pragma unroll
      for (int nj = 0; nj < 4; ++nj)
        acc[mi][nj] = MFMA_(Af[mi], Bf[nj], acc[mi][nj], 0, 0, 0);
    __builtin_amdgcn_s_setprio(0);
    __builtin_amdgcn_sched_barrier(0);
    __builtin_amdgcn_s_barrier();            // all waves done reading buf[k&1]
    if (k + 2 < NT) {
      unsigned short* d = smem + (k & 1) * 8192;
      stage128<1024>(xb, m0, (k + 2) * 32, d,        tid);
      stage128<1024>(W,  n0, (k + 2) * 32, d + 4096, tid);
    }
    if (k + 1 < NT) {
      if (k + 2 < NT) asm volatile("s_waitcnt vmcnt(4)" ::: "memory");
      else            asm volatile("s_waitcnt vmcnt(0)" ::: "memory");
      __builtin_amdgcn_s_barrier();          // publish buf[(k+1)&1]
    }
  }

  if (z < 2) {
    unsigned short* out = (z == 0) ? oVr : oVi;
#pragma unroll
    for (int nj = 0; nj < 4; ++nj) {
      int col = n0 + wc * 64 + nj * 16 + lr;
      float bv = bias[col];
#pragma unroll
      for (int mi = 0; mi < 4; ++mi) {
        int rowb = m0 + wr * 64 + mi * 16 + lq * 4;
#pragma unroll
        for (int r = 0; r < 4; ++r)
          out[(size_t)(rowb + r) * DD + col] = f2bf(acc[mi][nj][r] + bv);
      }
    }
  } else {
    // transposed epilogue through LDS, coalesced [b][d][n] store + sumsq
    __syncthreads();
    unsigned short* outp = (z == 2) ? Kt : Qt;
    const int which = z - 2;
    const int b = m0 >> 12;
    const int nbase = m0 & 4095;
    float* racc = rnacc + which * (BB * DD) + b * DD;
    unsigned short* T = smem;       // [128 d][136] shorts = 34.8 KB <= 36 KB
    const int SP2 = 136;
#pragma unroll
    for (int nj = 0; nj < 4; ++nj) {
      int cloc = wc * 64 + nj * 16 + lr;
      float bv = bias[n0 + cloc];
#pragma unroll
      for (int mi = 0; mi < 4; ++mi) {
        int rowb = wr * 64 + mi * 16 + lq * 4;
        ushort4 pk;
        pk.x = f2bf(acc[mi][nj][0] + bv); pk.y = f2bf(acc[mi][nj][1] + bv);
        pk.z = f2bf(acc[mi][nj][2] + bv); pk.w = f2bf(acc[mi][nj][3] + bv);
        *(ushort4*)(T + cloc * SP2 + rowb) = pk;   // 8B aligned (136 = 8*17)
      }
    }
    __syncthreads();
    // copy out: 16 lanes cover one d-row (128 n = 256B), 16 rows/pass, 8 passes
#pragma unroll
    for (int p = 0; p < 8; ++p) {
      int dl = p * 16 + (tid >> 4);
      int nc = (tid & 15) * 8;
      ushort4 v0 = *(const ushort4*)(T + dl * SP2 + nc);
      ushort4 v1 = *(const ushort4*)(T + dl * SP2 + nc + 4);
      int d = n0 + dl;
      *(ushort4*)(outp + (size_t)(b * DD + d) * NSEQ + nbase + nc)     = v0;
      *(ushort4*)(outp + (size_t)(b * DD + d) * NSEQ + nbase + nc + 4) = v1;
      float s = bf2f(v0.x)*bf2f(v0.x) + bf2f(v0.y)*bf2f(v0.y) + bf2f(v0.z)*bf2f(v0.z) + bf2f(v0.w)*bf2f(v0.w)
              + bf2f(v1.x)*bf2f(v1.x) + bf2f(v1.y)*bf2f(v1.y) + bf2f(v1.z)*bf2f(v1.z) + bf2f(v1.w)*bf2f(v1.w);
#pragma unroll
      for (int off = 1; off < 16; off <<= 1) s += __shfl_xor(s, off, 16);
      if ((tid & 15) == 0) atomicAdd(&racc[d], s);
    }
  }
}

// ---------------- finalize reciprocal norms ----------------
__global__ void finalize_rn(float* __restrict__ rn) {
  int i = blockIdx.x * blockDim.x + threadIdx.x;
  rn[i] = 1.f / (sqrtf(rn[i]) + 1e-5f);
}

// ---------------- GLU: V = Vr * tanh(softplus(Vi)), in place on Vr ----------------
__global__ void glu(unsigned short* __restrict__ V, const unsigned short* __restrict__ Vi, int n) {
  int i = (blockIdx.x * blockDim.x + threadIdx.x) * 8;
  if (i >= n) return;
  ushort4 r0 = *(const ushort4*)(V + i);
  ushort4 r1 = *(const ushort4*)(V + i + 4);
  ushort4 i0 = *(const ushort4*)(Vi + i);
  ushort4 i1 = *(const ushort4*)(Vi + i + 4);
  unsigned short vr[8] = {r0.x, r0.y, r0.z, r0.w, r1.x, r1.y, r1.z, r1.w};
  unsigned short vi[8] = {i0.x, i0.y, i0.z, i0.w, i1.x, i1.y, i1.z, i1.w};
  unsigned short o[8];
#pragma unroll
  for (int k = 0; k < 8; k++) {
    float a = bf2f(vr[k]), b = bf2f(vi[k]);
    float g;
    if (b > 10.f) g = 1.f;
    else { float t = __expf(b); float u = t * (t + 2.f); g = u / (u + 2.f); }
    o[k] = f2bf(a * g);
  }
  *(ushort4*)(V + i)     = make_ushort4(o[0], o[1], o[2], o[3]);
  *(ushort4*)(V + i + 4) = make_ushort4(o[4], o[5], o[6], o[7]);
}

// ---------------- feature attention (256x128 tile, BK=64, 2-phase/tile) --------
// (round-4 known-good version, unchanged)
__global__ __launch_bounds__(512, 2) void attn_gemm(
    const unsigned short* __restrict__ Qt, const unsigned short* __restrict__ Kt,
    const float* __restrict__ rn, unsigned short* __restrict__ fat) {
  __shared__ __align__(16) unsigned short smem[57344];

  const int b = blockIdx.z;
  const int d0 = blockIdx.x * 128;
  const int e0 = blockIdx.y * 256;
  const unsigned short* A  = Qt + (size_t)b * DD * NSEQ;
  const unsigned short* Bm = Kt + (size_t)b * DD * NSEQ;
  unsigned short* out = fat + (size_t)b * DD * DD;

  const int tid = threadIdx.x;
  const int w = tid >> 6, lane = tid & 63;
  const int wr = w >> 1, wc = w & 1;
  const int lq = lane >> 4, lr = lane & 15;
  const int sx = lr & 7;
  const int arow0 = wr * 64 + lr;
  const int brow0 = wc * 64 + lr;

  f32x4 acc[4][4];
#pragma unroll
  for (int i = 0; i < 4; i++)
#pragma unroll
    for (int j = 0; j < 4; j++) acc[i][j] = (f32x4)(0.f);

  const int NT = 64;

  const unsigned sbase = lds_off(smem);
  const unsigned sw0 = (unsigned)((lq ^ sx) << 4);
  const unsigned sw1 = (unsigned)(((4 | lq) ^ sx) << 4);
  unsigned aA0 = sbase + arow0 * 128 + sw0;
  unsigned aA1 = sbase + arow0 * 128 + sw1;
  unsigned aB0 = sbase + 32768 + brow0 * 128 + sw0;
  unsigned aB1 = sbase + 32768 + brow0 * 128 + sw1;

  stage_half<NSEQ>(A,  e0,       0,  smem,                 tid);
  stage_half<NSEQ>(A,  e0 + 128, 0,  smem + 8192,          tid);
  stage_half<NSEQ>(Bm, d0,       0,  smem + 16384,         tid);
  stage_half<NSEQ>(Bm, d0,       64, smem + 32768 + 16384, tid);
  asm volatile("s_waitcnt vmcnt(2)" ::: "memory");
  __builtin_amdgcn_s_barrier();

  for (int t = 0; t < NT; ++t) {
    bf16x8 bfr[4][2], aL[2][2];
    DSRI(aL[0][0], aA0, 0);    DSRI(aL[0][1], aA1, 0);
    DSRI(bfr[0][0], aB0, 0);    DSRI(bfr[0][1], aB1, 0);
    DSRI(bfr[1][0], aB0, 2048); DSRI(bfr[1][1], aB1, 2048);
    DSRI(bfr[2][0], aB0, 4096); DSRI(bfr[2][1], aB1, 4096);
    DSRI(bfr[3][0], aB0, 6144); DSRI(bfr[3][1], aB1, 6144);
    DSRI(aL[1][0], aA0, 2048); DSRI(aL[1][1], aA1, 2048);
    if (t + 1 < NT) {
      stage_half<NSEQ>(A, e0,       (t + 1) * 64, smem + ((t + 1) & 1) * 32768, tid);
      stage_half<NSEQ>(A, e0 + 128, (t + 1) * 64, smem + ((t + 1) & 1) * 32768 + 8192, tid);
    }
    __builtin_amdgcn_s_barrier();
    asm volatile("s_waitcnt lgkmcnt(2)" ::: "memory");
    __builtin_amdgcn_sched_barrier(0);
    __builtin_amdgcn_s_setprio(1);
#pragma unroll
    for (int nj = 0; nj < 4; ++nj) {
      acc[0][nj] = MFMA_(aL[0][0], bfr[nj][0], acc[0][nj], 0, 0, 0);
      acc[0][nj] = MFMA_(aL[0][1], bfr[nj][1], acc[0][nj], 0, 0, 0);
    }
    asm volatile("s_waitcnt lgkmcnt(0)" ::: "memory");
    __builtin_amdgcn_sched_barrier(0);
#pragma unroll
    for (int nj = 0; nj < 4; ++nj) {
      acc[1][nj] = MFMA_(aL[1][0], bfr[nj][0], acc[1][nj], 0, 0, 0);
      acc[1][nj] = MFMA_(aL[1][1], bfr[nj][1], acc[1][nj], 0, 0, 0);
    }
    __builtin_amdgcn_s_setprio(0);
    __builtin_amdgcn_sched_barrier(0);
    __builtin_amdgcn_s_barrier();

    bf16x8 aH[2][2];
    DSRI(aH[0][0], aA0, 4096); DSRI(aH[0][1], aA1, 4096);
    DSRI(aH[1][0], aA0, 6144); DSRI(aH[1][1], aA1, 6144);
    if (t + 2 < NT) {
      stage_half<NSEQ>(Bm, d0, (t + 2) * 64, smem + (t & 1) * 32768 + 16384, tid);
    }
    __builtin_amdgcn_s_barrier();
    asm volatile("s_waitcnt lgkmcnt(2)" ::: "memory");
    __builtin_amdgcn_sched_barrier(0);
    __builtin_amdgcn_s_setprio(1);
#pragma unroll
    for (int nj = 0; nj < 4; ++nj) {
      acc[2][nj] = MFMA_(aH[0][0], bfr[nj][0], acc[2][nj], 0, 0, 0);
      acc[2][nj] = MFMA_(aH[0][1], bfr[nj][1], acc[2][nj], 0, 0, 0);
    }
    asm volatile("s_waitcnt lgkmcnt(0)" ::: "memory");
    __builtin_amdgcn_sched_barrier(0);
#pragma unroll
    for (int nj = 0; nj < 4; ++nj) {
      acc[3][nj] = MFMA_(aH[1][0], bfr[nj][0], acc[3][nj], 0, 0, 0);
      acc[3][nj] = MFMA_(aH[1][1], bfr[nj][1], acc[3][nj], 0, 0, 0);
    }
    __builtin_amdgcn_s_setprio(0);
    __builtin_amdgcn_sched_barrier(0);
    if (t < NT - 2)       asm volatile("s_waitcnt vmcnt(2)" ::: "memory");
    else if (t == NT - 2) asm volatile("s_waitcnt vmcnt(0)" ::: "memory");
    __builtin_amdgcn_s_barrier();

    aA0 ^= 65536u; aA1 ^= 65536u; aB0 ^= 65536u; aB1 ^= 65536u;
  }

#pragma unroll
  for (int nj = 0; nj < 4; ++nj) {
    int col = d0 + wc * 64 + nj * 16 + lr;
    float rk = rn[b * DD + col];
#pragma unroll
    for (int mi = 0; mi < 4; ++mi) {
      int rowb = e0 + wr * 64 + mi * 16 + lq * 4;
#pragma unroll
      for (int r = 0; r < 4; ++r) {
        float rq = rn[BB * DD + b * DD + rowb + r];
        float c = acc[mi][nj][r] * rq * rk;
        c = (c > 0.f) ? c : 0.25f * c;   // smu(mu=1e6) == leaky relu
        out[(size_t)(rowb + r) * DD + col] = f2bf(c);
      }
    }
  }
}

// ---------------- output GEMM (128^2 tile, BK=32, 4 blocks/CU) -----------------
// out[m][e] = V[m][d] . fat[e][d]
__global__ __launch_bounds__(256, 4) void out_gemm(
    const unsigned short* __restrict__ V, const unsigned short* __restrict__ fat,
    float* __restrict__ out) {
  __shared__ __align__(16) unsigned short smem[18432];

  const int bx = blockIdx.x;
  const int swz = (bx & 7) * 256 + (bx >> 3);
  const int m0 = (swz >> 3) * 128;
  const int e0 = (swz & 7) * 128;
  const int b = m0 >> 12;
  const unsigned short* Bm = fat + (size_t)b * DD * DD;

  const int tid = threadIdx.x;
  const int w = tid >> 6, lane = tid & 63;
  const int wr = w >> 1, wc = w & 1;
  const int lq = lane >> 4, lr = lane & 15;
  const int key = (lr >> 1) & 3;
  const int arow0 = wr * 64 + lr;
  const int brow0 = wc * 64 + lr;

  f32x4 acc[4][4];
#pragma unroll
  for (int i = 0; i < 4; i++)
#pragma unroll
    for (int j = 0; j < 4; j++) acc[i][j] = (f32x4)(0.f);

  const int NT = 32;

  const unsigned sbase = lds_off(smem);
  const unsigned swsl = (unsigned)((lq ^ key) << 4);
  unsigned aA[2], aB[2];
#pragma unroll
  for (int i = 0; i < 2; ++i) {
    aA[i] = sbase + i * 16384u + (unsigned)(arow0 * 64) + swsl;
    aB[i] = sbase + i * 16384u + 8192u + (unsigned)(brow0 * 64) + swsl;
  }

  stage128<1024>(V,  m0, 0,  smem,               tid);
  stage128<1024>(Bm, e0, 0,  smem + 4096,        tid);
  stage128<1024>(V,  m0, 32, smem + 8192,        tid);
  stage128<1024>(Bm, e0, 32, smem + 8192 + 4096, tid);
  asm volatile("s_waitcnt vmcnt(4)" ::: "memory");
  __builtin_amdgcn_s_barrier();

#pragma unroll
  for (int k = 0; k < NT; ++k) {
    const unsigned rA = aA[k & 1], rB = aB[k & 1];
    bf16x8 Af[4], Bf[4];
    DSRI(Af[0], rA, 0);
    DSRI(Bf[0], rB, 0);    DSRI(Bf[1], rB, 1024);
    DSRI(Bf[2], rB, 2048); DSRI(Bf[3], rB, 3072);
    DSRI(Af[1], rA, 1024); DSRI(Af[2], rA, 2048); DSRI(Af[3], rA, 3072);
    asm volatile("s_waitcnt lgkmcnt(3)" ::: "memory");
    __builtin_amdgcn_sched_barrier(0);
    __builtin_amdgcn_s_setprio(1);
#pragma unroll
    for (int nj = 0; nj < 4; ++nj)
      acc[0][nj] = MFMA_(Af[0], Bf[nj], acc[0][nj], 0, 0, 0);
    asm volatile("s_waitcnt lgkmcnt(0)" ::: "memory");
    __builtin_amdgcn_sched_barrier(0);
#pragma unroll
    for (int mi = 1; mi < 4; ++mi)
#pragma unroll
      for (int nj = 0; nj < 4; ++nj)
        acc[mi][nj] = MFMA_(Af[mi], Bf[nj], acc[mi][nj], 0, 0, 0);
    __builtin_amdgcn_s_setprio(0);
    __builtin_amdgcn_sched_barrier(0);
    __builtin_amdgcn_s_barrier();
    if (k + 2 < NT) {
      unsigned short* d = smem + (k & 1) * 8192;
      stage128<1024>(V,  m0, (k + 2) * 32, d,        tid);
      stage128<1024>(Bm, e0, (k + 2) * 32, d + 4096, tid);
    }
    if (k + 1 < NT) {
      if (k + 2 < NT) asm volatile("s_waitcnt vmcnt(4)" ::: "memory");
      else            asm volatile("s_waitcnt vmcnt(0)" ::: "memory");
      __builtin_amdgcn_s_barrier();
    }
  }

#pragma unroll
  for (int nj = 0; nj < 4; ++nj) {
    int col = e0 + wc * 64 + nj * 16 + lr;
#pragma unroll
    for (int mi = 0; mi < 4; ++mi) {
      int rowb = m0 + wr * 64 + mi * 16 + lq * 4;
#pragma unroll
      for (int r = 0; r < 4; ++r)
        out[(size_t)(rowb + r) * DD + col] = acc[mi][nj][r];
    }
  }
}

extern "C" void kernel_launch(void* const* d_in, const int* in_sizes, int n_in,
                              void* d_out, int out_size, void* d_ws, size_t ws_size,
                              hipStream_t stream) {
  const float* x   = (const float*)d_in[0];
  const float* Wvr = (const float*)d_in[1];
  const float* bvr = (const float*)d_in[2];
  const float* Wvi = (const float*)d_in[3];
  const float* bvi = (const float*)d_in[4];
  const float* Wk  = (const float*)d_in[5];
  const float* bk  = (const float*)d_in[6];
  const float* Wq  = (const float*)d_in[7];
  const float* bq  = (const float*)d_in[8];
  float* out = (float*)d_out;

  char* p = (char*)d_ws;
  unsigned short* xb  = (unsigned short*)p; p += (size_t)MTOT * DD * 2;      // 64 MiB
  unsigned short* Wb  = (unsigned short*)p; p += 4ull * DD * DD * 2;         // 8 MiB
  unsigned short* Kt  = (unsigned short*)p; p += (size_t)BB * DD * NSEQ * 2; // 64 MiB
  unsigned short* Qt  = (unsigned short*)p; p += (size_t)BB * DD * NSEQ * 2; // 64 MiB
  unsigned short* Vb  = (unsigned short*)p; p += (size_t)MTOT * DD * 2;      // 64 MiB
  unsigned short* fat = (unsigned short*)p; p += (size_t)BB * DD * DD * 2;   // 16 MiB
  float* rn = (float*)p; p += 2ull * BB * DD * sizeof(float);                // 64 KiB

  // Vi staged in d_out (128 MiB fp32 out buffer; first 64 MiB as bf16 scratch)
  unsigned short* ViBuf = (unsigned short*)d_out;

  int nx = MTOT * DD;
  int nw = DD * DD;
  cvt_bf16<<<nx / 8 / 256, 256, 0, stream>>>(x, xb, nx);
  cvt_w<<<dim3(nw / 8 / 256, 4), 256, 0, stream>>>(Wvr, Wvi, Wk, Wq, Wb);
  hipMemsetAsync(rn, 0, 2ull * BB * DD * sizeof(float), stream);

  proj_all<<<dim3(2048, 1, 4), 256, 0, stream>>>(
      xb, Wb, bvr, bvi, bk, bq, Vb, ViBuf, Kt, Qt, rn);

  glu<<<nx / 8 / 256, 256, 0, stream>>>(Vb, ViBuf, nx);
  finalize_rn<<<2 * BB * DD / 256, 256, 0, stream>>>(rn);

  attn_gemm<<<dim3(DD / 128, DD / 256, BB), 512, 0, stream>>>(Qt, Kt, rn, fat);
  out_gemm<<<dim3(2048), 256, 0, stream>>>(Vb, fat, out);
}

// Round 7
// 717.029 us; speedup vs baseline: 1.0710x; 1.0710x over previous
//
#include <hip/hip_runtime.h>
#include <math.h>

typedef __bf16 bf16x8 __attribute__((ext_vector_type(8)));
typedef float f32x4 __attribute__((ext_vector_type(4)));

#define MTOT 32768   // B*N
#define DD   1024
#define NSEQ 4096
#define BB   8

__device__ __forceinline__ void async16(const void* gp, void* lp) {
  __builtin_amdgcn_global_load_lds(
      (__attribute__((address_space(1))) void*)(const_cast<void*>(gp)),
      (__attribute__((address_space(3))) void*)(lp), 16, 0, 0);
}

__device__ __forceinline__ unsigned short f2bf(float f) {
  union { float f; unsigned int u; } v; v.f = f;
  unsigned int r = v.u + 0x7fffu + ((v.u >> 16) & 1u);
  return (unsigned short)(r >> 16);
}
__device__ __forceinline__ float bf2f(unsigned short u) {
  union { unsigned int u; float f; } v; v.u = ((unsigned int)u) << 16; return v.f;
}
__device__ __forceinline__ unsigned pk2(float a, float b) {
  return (unsigned)f2bf(a) | ((unsigned)f2bf(b) << 16);
}

// DS byte address of an LDS object (compiler-sanctioned addrspacecast).
__device__ __forceinline__ unsigned lds_off(void* p) {
  return (unsigned)(unsigned long long)
      (__attribute__((address_space(3))) void*)p;
}
// Inline-asm ds_read_b128 with compile-time offset immediate.
// Rule-18: every consumer cluster gated by explicit lgkmcnt + sched_barrier(0).
#define DSRI(dst, base, off) \
  asm volatile("ds_read_b128 %0, %1 offset:" #off : "=v"(dst) : "v"(base))

#define MFMA_ __builtin_amdgcn_mfma_f32_16x16x32_bf16

// ---------------- fp32 -> bf16 convert (x) ----------------
__global__ void cvt_bf16(const float* __restrict__ in, unsigned short* __restrict__ out, int n) {
  int i = (blockIdx.x * blockDim.x + threadIdx.x) * 8;
  if (i >= n) return;
  float4 a = *(const float4*)(in + i);
  float4 b = *(const float4*)(in + i + 4);
  ushort4 o0, o1;
  o0.x = f2bf(a.x); o0.y = f2bf(a.y); o0.z = f2bf(a.z); o0.w = f2bf(a.w);
  o1.x = f2bf(b.x); o1.y = f2bf(b.y); o1.z = f2bf(b.z); o1.w = f2bf(b.w);
  *(ushort4*)(out + i) = o0;
  *(ushort4*)(out + i + 4) = o1;
}

// ---------------- weights: 4 matrices in one dispatch ----------------
__global__ void cvt_w(const float* __restrict__ w0, const float* __restrict__ w1,
                      const float* __restrict__ w2, const float* __restrict__ w3,
                      unsigned short* __restrict__ out) {
  int z = blockIdx.y;
  const float* in = (z == 0) ? w0 : (z == 1) ? w1 : (z == 2) ? w2 : w3;
  int i = (blockIdx.x * blockDim.x + threadIdx.x) * 8;
  float4 a = *(const float4*)(in + i);
  float4 b = *(const float4*)(in + i + 4);
  ushort4 o0, o1;
  o0.x = f2bf(a.x); o0.y = f2bf(a.y); o0.z = f2bf(a.z); o0.w = f2bf(a.w);
  o1.x = f2bf(b.x); o1.y = f2bf(b.y); o1.z = f2bf(b.z); o1.w = f2bf(b.w);
  unsigned short* o = out + (size_t)z * DD * DD;
  *(ushort4*)(o + i) = o0;
  *(ushort4*)(o + i + 4) = o1;
}

// Stage one 128x64 bf16 half-tile into a LINEAR LDS region via global_load_lds.
// T2 swizzle on the GLOBAL SOURCE side (rule 21): LDS slot s of row r receives
// global slot s ^ (r&7); the swizzled ds_reads apply the same XOR.
template<int LDG>
__device__ __forceinline__ void stage_half(const unsigned short* __restrict__ g,
                                           int row0, int k0,
                                           unsigned short* lds, int tid) {
#pragma unroll
  for (int l = 0; l < 2; ++l) {
    int u = l * 512 + tid;           // 16B unit within the 16 KiB half-tile
    int r = u >> 3;                  // row within half (0..127)
    int sl = (u & 7) ^ (r & 7);      // pre-swizzled source slot
    async16(g + (size_t)(row0 + r) * LDG + k0 + sl * 8, (char*)lds + u * 16);
  }
}

// ---------------- unified projection GEMM (256^2 tile, BK=64, 2-phase/tile) ----
// z: 0 = fused V (two passes: Wvi then Wvr, GLU in-register, writes Vb only)
//    1 = K (transposed out + sumsq), 2 = Q (same)
__global__ __launch_bounds__(512, 2) void proj_all(
    const unsigned short* __restrict__ xb,
    const unsigned short* __restrict__ Wb,
    const float* __restrict__ bvr, const float* __restrict__ bvi,
    const float* __restrict__ bk,  const float* __restrict__ bq,
    unsigned short* __restrict__ oV,
    unsigned short* __restrict__ Kt,  unsigned short* __restrict__ Qt,
    float* __restrict__ rnacc) {
  // 2 dbuf x (A 256x64 + B 256x64) bf16 = 128 KiB
  __shared__ __align__(16) unsigned short smem[65536];

  const int bx = blockIdx.x;
  const int swz = (bx & 7) * 64 + (bx >> 3);   // bijective XCD swizzle (512 = 8*64)
  const int m0 = (swz >> 2) * 256;
  const int n0 = (swz & 3) * 256;
  const int z = blockIdx.z;

  const int tid = threadIdx.x;
  const int w = tid >> 6, lane = tid & 63;
  const int wr = w >> 2, wc = w & 3;           // 2x4 wave grid; wave owns 128x64
  const int lq = lane >> 4, lr = lane & 15;
  const int sx = lr & 7;                       // read-side swizzle key (row & 7)
  const int arow0 = wr * 128 + lr;
  const int brow0 = wc * 64 + lr;

  f32x4 acc[8][4];
#pragma unroll
  for (int i = 0; i < 8; i++)
#pragma unroll
    for (int j = 0; j < 4; j++) acc[i][j] = (f32x4)(0.f);

  // packed Vi (bf16 pairs) for the fused z=0 path; constant-indexed only
  unsigned pkx[8][4], pky[8][4];

  const int NT = 16;  // K=1024 / BK=64

  // precomputed DS byte addresses (buf0); parity toggled by ^0x10000
  const unsigned sbase = lds_off(smem);
  const unsigned sw0 = (unsigned)((lq ^ sx) << 4);
  const unsigned sw1 = (unsigned)(((4 | lq) ^ sx) << 4);
  unsigned aA0 = sbase + arow0 * 128 + sw0;
  unsigned aA1 = sbase + arow0 * 128 + sw1;
  unsigned aB0 = sbase + 32768 + brow0 * 128 + sw0;
  unsigned aB1 = sbase + 32768 + brow0 * 128 + sw1;

  const int npass = (z == 0) ? 2 : 1;
  for (int pass = 0; pass < npass; ++pass) {
    // pass 0 of fused V uses Wvi (slot 1); pass 1 uses Wvr (slot 0).
    // z=1 -> Wk (slot 2), z=2 -> Wq (slot 3).
    const unsigned short* W =
        (z == 0) ? (Wb + (size_t)(pass == 0 ? 1 : 0) * DD * DD)
                 : (Wb + (size_t)(z + 1) * DD * DD);

    // prologue: A(0) h0,h1 ; B(0) h0,h1 -> buf0 ; B(1) h0,h1 -> buf1 (12 loads)
    stage_half<1024>(xb, m0,       0,  smem,                     tid);
    stage_half<1024>(xb, m0 + 128, 0,  smem + 8192,              tid);
    stage_half<1024>(W,  n0,       0,  smem + 16384,             tid);
    stage_half<1024>(W,  n0 + 128, 0,  smem + 16384 + 8192,      tid);
    stage_half<1024>(W,  n0,       64, smem + 32768 + 16384,     tid);
    stage_half<1024>(W,  n0 + 128, 64, smem + 32768 + 16384 + 8192, tid);
    asm volatile("s_waitcnt vmcnt(4)" ::: "memory");  // tile0 landed, B(1) in flight
    __builtin_amdgcn_s_barrier();

    for (int t = 0; t < NT; ++t) {
      // ================= phase 0: MFMA mi0-3; stage A(t+1) =================
      bf16x8 bfr[4][2], aL[4][2];
      DSRI(aL[0][0], aA0, 0);    DSRI(aL[0][1], aA1, 0);
      DSRI(bfr[0][0], aB0, 0);    DSRI(bfr[0][1], aB1, 0);
      DSRI(bfr[1][0], aB0, 2048); DSRI(bfr[1][1], aB1, 2048);
      DSRI(bfr[2][0], aB0, 4096); DSRI(bfr[2][1], aB1, 4096);
      DSRI(bfr[3][0], aB0, 6144); DSRI(bfr[3][1], aB1, 6144);
      DSRI(aL[1][0], aA0, 2048); DSRI(aL[1][1], aA1, 2048);
      DSRI(aL[2][0], aA0, 4096); DSRI(aL[2][1], aA1, 4096);
      DSRI(aL[3][0], aA0, 6144); DSRI(aL[3][1], aA1, 6144);
      if (t + 1 < NT) {
        stage_half<1024>(xb, m0,       (t + 1) * 64, smem + ((t + 1) & 1) * 32768, tid);
        stage_half<1024>(xb, m0 + 128, (t + 1) * 64, smem + ((t + 1) & 1) * 32768 + 8192, tid);
      }
      __builtin_amdgcn_s_barrier();
      asm volatile("s_waitcnt lgkmcnt(6)" ::: "memory");  // aL[0] + all B landed
      __builtin_amdgcn_sched_barrier(0);
      __builtin_amdgcn_s_setprio(1);
#pragma unroll
      for (int nj = 0; nj < 4; ++nj) {
        acc[0][nj] = MFMA_(aL[0][0], bfr[nj][0], acc[0][nj], 0, 0, 0);
        acc[0][nj] = MFMA_(aL[0][1], bfr[nj][1], acc[0][nj], 0, 0, 0);
      }
      asm volatile("s_waitcnt lgkmcnt(0)" ::: "memory");  // aL[1..3] landed
      __builtin_amdgcn_sched_barrier(0);
#pragma unroll
      for (int mi = 1; mi < 4; ++mi)
#pragma unroll
        for (int nj = 0; nj < 4; ++nj) {
          acc[mi][nj] = MFMA_(aL[mi][0], bfr[nj][0], acc[mi][nj], 0, 0, 0);
          acc[mi][nj] = MFMA_(aL[mi][1], bfr[nj][1], acc[mi][nj], 0, 0, 0);
        }
      __builtin_amdgcn_s_setprio(0);
      __builtin_amdgcn_sched_barrier(0);
      __builtin_amdgcn_s_barrier();

      // ================= phase 1: MFMA mi4-7; stage B(t+2) =================
      bf16x8 aH[4][2];
      DSRI(aH[0][0], aA0, 8192);  DSRI(aH[0][1], aA1, 8192);
      DSRI(aH[1][0], aA0, 10240); DSRI(aH[1][1], aA1, 10240);
      DSRI(aH[2][0], aA0, 12288); DSRI(aH[2][1], aA1, 12288);
      DSRI(aH[3][0], aA0, 14336); DSRI(aH[3][1], aA1, 14336);
      if (t + 2 < NT) {
        stage_half<1024>(W, n0,       (t + 2) * 64, smem + (t & 1) * 32768 + 16384, tid);
        stage_half<1024>(W, n0 + 128, (t + 2) * 64, smem + (t & 1) * 32768 + 16384 + 8192, tid);
      }
      __builtin_amdgcn_s_barrier();
      asm volatile("s_waitcnt lgkmcnt(4)" ::: "memory");  // aH[0..1] landed
      __builtin_amdgcn_sched_barrier(0);
      __builtin_amdgcn_s_setprio(1);
#pragma unroll
      for (int mi = 0; mi < 2; ++mi)
#pragma unroll
        for (int nj = 0; nj < 4; ++nj) {
          acc[4 + mi][nj] = MFMA_(aH[mi][0], bfr[nj][0], acc[4 + mi][nj], 0, 0, 0);
          acc[4 + mi][nj] = MFMA_(aH[mi][1], bfr[nj][1], acc[4 + mi][nj], 0, 0, 0);
        }
      asm volatile("s_waitcnt lgkmcnt(0)" ::: "memory");  // aH[2..3] landed
      __builtin_amdgcn_sched_barrier(0);
#pragma unroll
      for (int mi = 2; mi < 4; ++mi)
#pragma unroll
        for (int nj = 0; nj < 4; ++nj) {
          acc[4 + mi][nj] = MFMA_(aH[mi][0], bfr[nj][0], acc[4 + mi][nj], 0, 0, 0);
          acc[4 + mi][nj] = MFMA_(aH[mi][1], bfr[nj][1], acc[4 + mi][nj], 0, 0, 0);
        }
      __builtin_amdgcn_s_setprio(0);
      __builtin_amdgcn_sched_barrier(0);
      if (t < NT - 2)       asm volatile("s_waitcnt vmcnt(4)" ::: "memory");
      else if (t == NT - 2) asm volatile("s_waitcnt vmcnt(0)" ::: "memory");
      __builtin_amdgcn_s_barrier();

      aA0 ^= 65536u; aA1 ^= 65536u; aB0 ^= 65536u; aB1 ^= 65536u;
    }

    if (z == 0 && pass == 0) {
      // pack Vi = bf16(acc + bvi) into registers, exactly replicating the old
      // proj-epilogue rounding; then reset acc for the Vr pass.
#pragma unroll
      for (int nj = 0; nj < 4; ++nj) {
        int col = n0 + wc * 64 + nj * 16 + lr;
        float bv = bvi[col];
#pragma unroll
        for (int mrep = 0; mrep < 8; ++mrep) {
          pkx[mrep][nj] = pk2(acc[mrep][nj][0] + bv, acc[mrep][nj][1] + bv);
          pky[mrep][nj] = pk2(acc[mrep][nj][2] + bv, acc[mrep][nj][3] + bv);
          acc[mrep][nj] = (f32x4)(0.f);
        }
      }
    }
  }

  if (z == 0) {
    // fused epilogue: V = bf16(Vr) * tanh(softplus(Vi)), numerics == old glu
#pragma unroll
    for (int nj = 0; nj < 4; ++nj) {
      int col = n0 + wc * 64 + nj * 16 + lr;
      float bv = bvr[col];
#pragma unroll
      for (int mrep = 0; mrep < 8; ++mrep) {
        int rowb = m0 + wr * 128 + mrep * 16 + lq * 4;
#pragma unroll
        for (int r = 0; r < 4; ++r) {
          float vr = bf2f(f2bf(acc[mrep][nj][r] + bv));
          unsigned p = (r < 2) ? pkx[mrep][nj] : pky[mrep][nj];
          float vi = bf2f((unsigned short)((r & 1) ? (p >> 16) : (p & 0xffffu)));
          float g;
          if (vi > 10.f) g = 1.f;
          else { float tt = __expf(vi); float u = tt * (tt + 2.f); g = u / (u + 2.f); }
          oV[(size_t)(rowb + r) * DD + col] = f2bf(vr * g);
        }
      }
    }
  } else {
    // transposed epilogue: two 128-col halves through LDS, coalesced [b][d][n] store + sumsq
    const float* bias = (z == 1) ? bk : bq;
    unsigned short* outp = (z == 1) ? Kt : Qt;
    const int which = z - 1;
    const int b = m0 >> 12;
    const int nbase = m0 & 4095;
    float* racc = rnacc + which * (BB * DD) + b * DD;
    unsigned short* T = smem;       // [128][264] shorts (67.6 KB <= 128 KB)
    const int SP2 = 264;
#pragma unroll
    for (int ch = 0; ch < 2; ++ch) {
      if ((wc >> 1) == ch) {
#pragma unroll
        for (int nj = 0; nj < 4; ++nj) {
          int cloc = (wc & 1) * 64 + nj * 16 + lr;
          float bv = bias[n0 + ch * 128 + cloc];
#pragma unroll
          for (int mrep = 0; mrep < 8; ++mrep) {
            int rowb = wr * 128 + mrep * 16 + lq * 4;
            ushort4 pk;
            pk.x = f2bf(acc[mrep][nj][0] + bv); pk.y = f2bf(acc[mrep][nj][1] + bv);
            pk.z = f2bf(acc[mrep][nj][2] + bv); pk.w = f2bf(acc[mrep][nj][3] + bv);
            *(ushort4*)(T + cloc * SP2 + rowb) = pk;   // 8B aligned
          }
        }
      }
      __syncthreads();
      // copy out: 32 lanes cover one d-row (256 n = 512B), 16 rows/pass, 8 passes
#pragma unroll
      for (int p = 0; p < 8; ++p) {
        int dl = p * 16 + (tid >> 5);
        int nc = (tid & 31) * 8;
        ushort4 v0 = *(const ushort4*)(T + dl * SP2 + nc);
        ushort4 v1 = *(const ushort4*)(T + dl * SP2 + nc + 4);
        int d = n0 + ch * 128 + dl;
        *(ushort4*)(outp + (size_t)(b * DD + d) * NSEQ + nbase + nc)     = v0;
        *(ushort4*)(outp + (size_t)(b * DD + d) * NSEQ + nbase + nc + 4) = v1;
        float s = bf2f(v0.x)*bf2f(v0.x) + bf2f(v0.y)*bf2f(v0.y) + bf2f(v0.z)*bf2f(v0.z) + bf2f(v0.w)*bf2f(v0.w)
                + bf2f(v1.x)*bf2f(v1.x) + bf2f(v1.y)*bf2f(v1.y) + bf2f(v1.z)*bf2f(v1.z) + bf2f(v1.w)*bf2f(v1.w);
#pragma unroll
        for (int off = 1; off < 32; off <<= 1) s += __shfl_xor(s, off, 32);
        if ((tid & 31) == 0) atomicAdd(&racc[d], s);
      }
      __syncthreads();
    }
  }
}

// ---------------- finalize reciprocal norms ----------------
__global__ void finalize_rn(float* __restrict__ rn) {
  int i = blockIdx.x * blockDim.x + threadIdx.x;
  rn[i] = 1.f / (sqrtf(rn[i]) + 1e-5f);
}

// ---------------- feature attention (256x128 tile, BK=64, 2-phase/tile) --------
__global__ __launch_bounds__(512, 2) void attn_gemm(
    const unsigned short* __restrict__ Qt, const unsigned short* __restrict__ Kt,
    const float* __restrict__ rn, unsigned short* __restrict__ fat) {
  __shared__ __align__(16) unsigned short smem[57344];

  const int b = blockIdx.z;
  const int d0 = blockIdx.x * 128;
  const int e0 = blockIdx.y * 256;
  const unsigned short* A  = Qt + (size_t)b * DD * NSEQ;
  const unsigned short* Bm = Kt + (size_t)b * DD * NSEQ;
  unsigned short* out = fat + (size_t)b * DD * DD;

  const int tid = threadIdx.x;
  const int w = tid >> 6, lane = tid & 63;
  const int wr = w >> 1, wc = w & 1;
  const int lq = lane >> 4, lr = lane & 15;
  const int sx = lr & 7;
  const int arow0 = wr * 64 + lr;
  const int brow0 = wc * 64 + lr;

  f32x4 acc[4][4];
#pragma unroll
  for (int i = 0; i < 4; i++)
#pragma unroll
    for (int j = 0; j < 4; j++) acc[i][j] = (f32x4)(0.f);

  const int NT = 64;

  const unsigned sbase = lds_off(smem);
  const unsigned sw0 = (unsigned)((lq ^ sx) << 4);
  const unsigned sw1 = (unsigned)(((4 | lq) ^ sx) << 4);
  unsigned aA0 = sbase + arow0 * 128 + sw0;
  unsigned aA1 = sbase + arow0 * 128 + sw1;
  unsigned aB0 = sbase + 32768 + brow0 * 128 + sw0;
  unsigned aB1 = sbase + 32768 + brow0 * 128 + sw1;

  stage_half<NSEQ>(A,  e0,       0,  smem,                 tid);
  stage_half<NSEQ>(A,  e0 + 128, 0,  smem + 8192,          tid);
  stage_half<NSEQ>(Bm, d0,       0,  smem + 16384,         tid);
  stage_half<NSEQ>(Bm, d0,       64, smem + 32768 + 16384, tid);
  asm volatile("s_waitcnt vmcnt(2)" ::: "memory");
  __builtin_amdgcn_s_barrier();

  for (int t = 0; t < NT; ++t) {
    bf16x8 bfr[4][2], aL[2][2];
    DSRI(aL[0][0], aA0, 0);    DSRI(aL[0][1], aA1, 0);
    DSRI(bfr[0][0], aB0, 0);    DSRI(bfr[0][1], aB1, 0);
    DSRI(bfr[1][0], aB0, 2048); DSRI(bfr[1][1], aB1, 2048);
    DSRI(bfr[2][0], aB0, 4096); DSRI(bfr[2][1], aB1, 4096);
    DSRI(bfr[3][0], aB0, 6144); DSRI(bfr[3][1], aB1, 6144);
    DSRI(aL[1][0], aA0, 2048); DSRI(aL[1][1], aA1, 2048);
    if (t + 1 < NT) {
      stage_half<NSEQ>(A, e0,       (t + 1) * 64, smem + ((t + 1) & 1) * 32768, tid);
      stage_half<NSEQ>(A, e0 + 128, (t + 1) * 64, smem + ((t + 1) & 1) * 32768 + 8192, tid);
    }
    __builtin_amdgcn_s_barrier();
    asm volatile("s_waitcnt lgkmcnt(2)" ::: "memory");
    __builtin_amdgcn_sched_barrier(0);
    __builtin_amdgcn_s_setprio(1);
#pragma unroll
    for (int nj = 0; nj < 4; ++nj) {
      acc[0][nj] = MFMA_(aL[0][0], bfr[nj][0], acc[0][nj], 0, 0, 0);
      acc[0][nj] = MFMA_(aL[0][1], bfr[nj][1], acc[0][nj], 0, 0, 0);
    }
    asm volatile("s_waitcnt lgkmcnt(0)" ::: "memory");
    __builtin_amdgcn_sched_barrier(0);
#pragma unroll
    for (int nj = 0; nj < 4; ++nj) {
      acc[1][nj] = MFMA_(aL[1][0], bfr[nj][0], acc[1][nj], 0, 0, 0);
      acc[1][nj] = MFMA_(aL[1][1], bfr[nj][1], acc[1][nj], 0, 0, 0);
    }
    __builtin_amdgcn_s_setprio(0);
    __builtin_amdgcn_sched_barrier(0);
    __builtin_amdgcn_s_barrier();

    bf16x8 aH[2][2];
    DSRI(aH[0][0], aA0, 4096); DSRI(aH[0][1], aA1, 4096);
    DSRI(aH[1][0], aA0, 6144); DSRI(aH[1][1], aA1, 6144);
    if (t + 2 < NT) {
      stage_half<NSEQ>(Bm, d0, (t + 2) * 64, smem + (t & 1) * 32768 + 16384, tid);
    }
    __builtin_amdgcn_s_barrier();
    asm volatile("s_waitcnt lgkmcnt(2)" ::: "memory");
    __builtin_amdgcn_sched_barrier(0);
    __builtin_amdgcn_s_setprio(1);
#pragma unroll
    for (int nj = 0; nj < 4; ++nj) {
      acc[2][nj] = MFMA_(aH[0][0], bfr[nj][0], acc[2][nj], 0, 0, 0);
      acc[2][nj] = MFMA_(aH[0][1], bfr[nj][1], acc[2][nj], 0, 0, 0);
    }
    asm volatile("s_waitcnt lgkmcnt(0)" ::: "memory");
    __builtin_amdgcn_sched_barrier(0);
#pragma unroll
    for (int nj = 0; nj < 4; ++nj) {
      acc[3][nj] = MFMA_(aH[1][0], bfr[nj][0], acc[3][nj], 0, 0, 0);
      acc[3][nj] = MFMA_(aH[1][1], bfr[nj][1], acc[3][nj], 0, 0, 0);
    }
    __builtin_amdgcn_s_setprio(0);
    __builtin_amdgcn_sched_barrier(0);
    if (t < NT - 2)       asm volatile("s_waitcnt vmcnt(2)" ::: "memory");
    else if (t == NT - 2) asm volatile("s_waitcnt vmcnt(0)" ::: "memory");
    __builtin_amdgcn_s_barrier();

    aA0 ^= 65536u; aA1 ^= 65536u; aB0 ^= 65536u; aB1 ^= 65536u;
  }

#pragma unroll
  for (int nj = 0; nj < 4; ++nj) {
    int col = d0 + wc * 64 + nj * 16 + lr;
    float rk = rn[b * DD + col];
#pragma unroll
    for (int mi = 0; mi < 4; ++mi) {
      int rowb = e0 + wr * 64 + mi * 16 + lq * 4;
#pragma unroll
      for (int r = 0; r < 4; ++r) {
        float rq = rn[BB * DD + b * DD + rowb + r];
        float c = acc[mi][nj][r] * rq * rk;
        c = (c > 0.f) ? c : 0.25f * c;   // smu(mu=1e6) == leaky relu
        out[(size_t)(rowb + r) * DD + col] = f2bf(c);
      }
    }
  }
}

// ---------------- output GEMM (256^2 tile, BK=64, 2-phase/tile) ----------------
// out[m][e] = V[m][d] . fat[e][d]
__global__ __launch_bounds__(512, 2) void out_gemm(
    const unsigned short* __restrict__ V, const unsigned short* __restrict__ fat,
    float* __restrict__ out) {
  __shared__ __align__(16) unsigned short smem[65536];

  const int bx = blockIdx.x;
  const int swz = (bx & 7) * 64 + (bx >> 3);
  const int m0 = (swz >> 2) * 256;
  const int e0 = (swz & 3) * 256;
  const int b = m0 >> 12;
  const unsigned short* Bm = fat + (size_t)b * DD * DD;

  const int tid = threadIdx.x;
  const int w = tid >> 6, lane = tid & 63;
  const int wr = w >> 2, wc = w & 3;
  const int lq = lane >> 4, lr = lane & 15;
  const int sx = lr & 7;
  const int arow0 = wr * 128 + lr;
  const int brow0 = wc * 64 + lr;

  f32x4 acc[8][4];
#pragma unroll
  for (int i = 0; i < 8; i++)
#pragma unroll
    for (int j = 0; j < 4; j++) acc[i][j] = (f32x4)(0.f);

  const int NT = 16;

  const unsigned sbase = lds_off(smem);
  const unsigned sw0 = (unsigned)((lq ^ sx) << 4);
  const unsigned sw1 = (unsigned)(((4 | lq) ^ sx) << 4);
  unsigned aA0 = sbase + arow0 * 128 + sw0;
  unsigned aA1 = sbase + arow0 * 128 + sw1;
  unsigned aB0 = sbase + 32768 + brow0 * 128 + sw0;
  unsigned aB1 = sbase + 32768 + brow0 * 128 + sw1;

  stage_half<1024>(V,  m0,       0,  smem,                        tid);
  stage_half<1024>(V,  m0 + 128, 0,  smem + 8192,                 tid);
  stage_half<1024>(Bm, e0,       0,  smem + 16384,                tid);
  stage_half<1024>(Bm, e0 + 128, 0,  smem + 16384 + 8192,         tid);
  stage_half<1024>(Bm, e0,       64, smem + 32768 + 16384,        tid);
  stage_half<1024>(Bm, e0 + 128, 64, smem + 32768 + 16384 + 8192, tid);
  asm volatile("s_waitcnt vmcnt(4)" ::: "memory");
  __builtin_amdgcn_s_barrier();

  for (int t = 0; t < NT; ++t) {
    bf16x8 bfr[4][2], aL[4][2];
    DSRI(aL[0][0], aA0, 0);    DSRI(aL[0][1], aA1, 0);
    DSRI(bfr[0][0], aB0, 0);    DSRI(bfr[0][1], aB1, 0);
    DSRI(bfr[1][0], aB0, 2048); DSRI(bfr[1][1], aB1, 2048);
    DSRI(bfr[2][0], aB0, 4096); DSRI(bfr[2][1], aB1, 4096);
    DSRI(bfr[3][0], aB0, 6144); DSRI(bfr[3][1], aB1, 6144);
    DSRI(aL[1][0], aA0, 2048); DSRI(aL[1][1], aA1, 2048);
    DSRI(aL[2][0], aA0, 4096); DSRI(aL[2][1], aA1, 4096);
    DSRI(aL[3][0], aA0, 6144); DSRI(aL[3][1], aA1, 6144);
    if (t + 1 < NT) {
      stage_half<1024>(V, m0,       (t + 1) * 64, smem + ((t + 1) & 1) * 32768, tid);
      stage_half<1024>(V, m0 + 128, (t + 1) * 64, smem + ((t + 1) & 1) * 32768 + 8192, tid);
    }
    __builtin_amdgcn_s_barrier();
    asm volatile("s_waitcnt lgkmcnt(6)" ::: "memory");
    __builtin_amdgcn_sched_barrier(0);
    __builtin_amdgcn_s_setprio(1);
#pragma unroll
    for (int nj = 0; nj < 4; ++nj) {
      acc[0][nj] = MFMA_(aL[0][0], bfr[nj][0], acc[0][nj], 0, 0, 0);
      acc[0][nj] = MFMA_(aL[0][1], bfr[nj][1], acc[0][nj], 0, 0, 0);
    }
    asm volatile("s_waitcnt lgkmcnt(0)" ::: "memory");
    __builtin_amdgcn_sched_barrier(0);
#pragma unroll
    for (int mi = 1; mi < 4; ++mi)
#pragma unroll
      for (int nj = 0; nj < 4; ++nj) {
        acc[mi][nj] = MFMA_(aL[mi][0], bfr[nj][0], acc[mi][nj], 0, 0, 0);
        acc[mi][nj] = MFMA_(aL[mi][1], bfr[nj][1], acc[mi][nj], 0, 0, 0);
      }
    __builtin_amdgcn_s_setprio(0);
    __builtin_amdgcn_sched_barrier(0);
    __builtin_amdgcn_s_barrier();

    bf16x8 aH[4][2];
    DSRI(aH[0][0], aA0, 8192);  DSRI(aH[0][1], aA1, 8192);
    DSRI(aH[1][0], aA0, 10240); DSRI(aH[1][1], aA1, 10240);
    DSRI(aH[2][0], aA0, 12288); DSRI(aH[2][1], aA1, 12288);
    DSRI(aH[3][0], aA0, 14336); DSRI(aH[3][1], aA1, 14336);
    if (t + 2 < NT) {
      stage_half<1024>(Bm, e0,       (t + 2) * 64, smem + (t & 1) * 32768 + 16384, tid);
      stage_half<1024>(Bm, e0 + 128, (t + 2) * 64, smem + (t & 1) * 32768 + 16384 + 8192, tid);
    }
    __builtin_amdgcn_s_barrier();
    asm volatile("s_waitcnt lgkmcnt(4)" ::: "memory");
    __builtin_amdgcn_sched_barrier(0);
    __builtin_amdgcn_s_setprio(1);
#pragma unroll
    for (int mi = 0; mi < 2; ++mi)
#pragma unroll
      for (int nj = 0; nj < 4; ++nj) {
        acc[4 + mi][nj] = MFMA_(aH[mi][0], bfr[nj][0], acc[4 + mi][nj], 0, 0, 0);
        acc[4 + mi][nj] = MFMA_(aH[mi][1], bfr[nj][1], acc[4 + mi][nj], 0, 0, 0);
      }
    asm volatile("s_waitcnt lgkmcnt(0)" ::: "memory");
    __builtin_amdgcn_sched_barrier(0);
#pragma unroll
    for (int mi = 2; mi < 4; ++mi)
#pragma unroll
      for (int nj = 0; nj < 4; ++nj) {
        acc[4 + mi][nj] = MFMA_(aH[mi][0], bfr[nj][0], acc[4 + mi][nj], 0, 0, 0);
        acc[4 + mi][nj] = MFMA_(aH[mi][1], bfr[nj][1], acc[4 + mi][nj], 0, 0, 0);
      }
    __builtin_amdgcn_s_setprio(0);
    __builtin_amdgcn_sched_barrier(0);
    if (t < NT - 2)       asm volatile("s_waitcnt vmcnt(4)" ::: "memory");
    else if (t == NT - 2) asm volatile("s_waitcnt vmcnt(0)" ::: "memory");
    __builtin_amdgcn_s_barrier();

    aA0 ^= 65536u; aA1 ^= 65536u; aB0 ^= 65536u; aB1 ^= 65536u;
  }

#pragma unroll
  for (int nj = 0; nj < 4; ++nj) {
    int col = e0 + wc * 64 + nj * 16 + lr;
#pragma unroll
    for (int mrep = 0; mrep < 8; ++mrep) {
      int rowb = m0 + wr * 128 + mrep * 16 + lq * 4;
#pragma unroll
      for (int r = 0; r < 4; ++r)
        out[(size_t)(rowb + r) * DD + col] = acc[mrep][nj][r];
    }
  }
}

extern "C" void kernel_launch(void* const* d_in, const int* in_sizes, int n_in,
                              void* d_out, int out_size, void* d_ws, size_t ws_size,
                              hipStream_t stream) {
  const float* x   = (const float*)d_in[0];
  const float* Wvr = (const float*)d_in[1];
  const float* bvr = (const float*)d_in[2];
  const float* Wvi = (const float*)d_in[3];
  const float* bvi = (const float*)d_in[4];
  const float* Wk  = (const float*)d_in[5];
  const float* bk  = (const float*)d_in[6];
  const float* Wq  = (const float*)d_in[7];
  const float* bq  = (const float*)d_in[8];
  float* out = (float*)d_out;

  char* p = (char*)d_ws;
  unsigned short* xb  = (unsigned short*)p; p += (size_t)MTOT * DD * 2;      // 64 MiB
  unsigned short* Wb  = (unsigned short*)p; p += 4ull * DD * DD * 2;         // 8 MiB
  unsigned short* Kt  = (unsigned short*)p; p += (size_t)BB * DD * NSEQ * 2; // 64 MiB
  unsigned short* Qt  = (unsigned short*)p; p += (size_t)BB * DD * NSEQ * 2; // 64 MiB
  unsigned short* Vb  = (unsigned short*)p; p += (size_t)MTOT * DD * 2;      // 64 MiB
  unsigned short* fat = (unsigned short*)p; p += (size_t)BB * DD * DD * 2;   // 16 MiB
  float* rn = (float*)p; p += 2ull * BB * DD * sizeof(float);                // 64 KiB

  int nx = MTOT * DD;
  int nw = DD * DD;
  cvt_bf16<<<nx / 8 / 256, 256, 0, stream>>>(x, xb, nx);
  cvt_w<<<dim3(nw / 8 / 256, 4), 256, 0, stream>>>(Wvr, Wvi, Wk, Wq, Wb);
  hipMemsetAsync(rn, 0, 2ull * BB * DD * sizeof(float), stream);

  // z: 0 = fused V (Vi pass + Vr pass + GLU), 1 = K, 2 = Q
  proj_all<<<dim3(512, 1, 3), 512, 0, stream>>>(
      xb, Wb, bvr, bvi, bk, bq, Vb, Kt, Qt, rn);

  finalize_rn<<<2 * BB * DD / 256, 256, 0, stream>>>(rn);

  attn_gemm<<<dim3(DD / 128, DD / 256, BB), 512, 0, stream>>>(Qt, Kt, rn, fat);
  out_gemm<<<dim3(512), 512, 0, stream>>>(Vb, fat, out);
}